// Round 4
// baseline (1697.957 us; speedup 1.0000x reference)
//
#include <hip/hip_runtime.h>
#include <float.h>

#define D 512
#define BM 128
#define BN 256
#define BK 32
#define NCH 64          // chunks over the point dim
#define MPC 8           // approx candidates kept per (query, chunk)
#define TR 16           // candidates exactly rescored per query

typedef __attribute__((ext_vector_type(8))) short short8;
typedef __attribute__((ext_vector_type(4))) float f32x4;
typedef const __attribute__((address_space(1))) void gv_t;
typedef __attribute__((address_space(3))) void lv_t;

__device__ __forceinline__ void gl2lds16(const void* g, void* l) {
    __builtin_amdgcn_global_load_lds((gv_t*)g, (lv_t*)l, 16, 0, 0);
}

__device__ __forceinline__ unsigned short f2bf(float f) {
    unsigned u = __float_as_uint(f);
    return (unsigned short)((u + 0x7FFF + ((u >> 16) & 1)) >> 16);
}

template <int K>
__device__ __forceinline__ void insertK(float* bs, int* bi, float v, int id) {
    if (v < bs[K - 1]) {
        bs[K - 1] = v; bi[K - 1] = id;
#pragma unroll
        for (int r = K - 1; r >= 1; --r) {
            if (bs[r] < bs[r - 1]) {
                float tf = bs[r]; bs[r] = bs[r - 1]; bs[r - 1] = tf;
                int ti = bi[r]; bi[r] = bi[r - 1]; bi[r - 1] = ti;
            }
        }
    }
}

// X fp32 -> bf16 (zero-padded rows) + exact fp32 ||x||^2 (1e30 for pad rows).
__global__ void convert_x(const float* __restrict__ X, unsigned short* __restrict__ Xbf,
                          float* __restrict__ xsq, int N, int padN) {
    int row = blockIdx.x * 4 + (threadIdx.x >> 6);
    int lane = threadIdx.x & 63;
    if (row >= padN) return;
    unsigned short ob[8];
    float s = 0.0f;
    if (row < N) {
        const float* p = X + (size_t)row * D + lane * 8;
        float4 a = *(const float4*)p;
        float4 b = *(const float4*)(p + 4);
        s = a.x * a.x + a.y * a.y + a.z * a.z + a.w * a.w
          + b.x * b.x + b.y * b.y + b.z * b.z + b.w * b.w;
        ob[0] = f2bf(a.x); ob[1] = f2bf(a.y); ob[2] = f2bf(a.z); ob[3] = f2bf(a.w);
        ob[4] = f2bf(b.x); ob[5] = f2bf(b.y); ob[6] = f2bf(b.z); ob[7] = f2bf(b.w);
    } else {
#pragma unroll
        for (int i = 0; i < 8; ++i) ob[i] = 0;
    }
    *(uint4*)(Xbf + (size_t)row * D + lane * 8) = *(uint4*)ob;
#pragma unroll
    for (int off = 32; off > 0; off >>= 1) s += __shfl_down(s, off, 64);
    if (lane == 0) xsq[row] = (row < N) ? s : 1e30f;
}

// Q fp32 -> bf16(-2*q).
__global__ void convert_q(const float* __restrict__ Q, unsigned short* __restrict__ Qbf) {
    int row = blockIdx.x * 4 + (threadIdx.x >> 6);
    int lane = threadIdx.x & 63;
    const float* p = Q + (size_t)row * D + lane * 8;
    float4 a = *(const float4*)p;
    float4 b = *(const float4*)(p + 4);
    unsigned short ob[8];
    ob[0] = f2bf(-2.0f * a.x); ob[1] = f2bf(-2.0f * a.y);
    ob[2] = f2bf(-2.0f * a.z); ob[3] = f2bf(-2.0f * a.w);
    ob[4] = f2bf(-2.0f * b.x); ob[5] = f2bf(-2.0f * b.y);
    ob[6] = f2bf(-2.0f * b.z); ob[7] = f2bf(-2.0f * b.w);
    *(uint4*)(Qbf + (size_t)row * D + lane * 8) = *(uint4*)ob;
}

struct KBuf { unsigned short A[BM * BK]; unsigned short B[BN * BK]; };  // 24576 B

// Stage one BKx(BM+BN) bf16 panel pair into LDS buffer bp_ (6 loads/wave).
// Source k-seg XOR-preswizzled so linear-LDS frag reads are bank-spread.
#define STAGE(bp_, nn0, kk0)                                                          \
    do {                                                                              \
        const size_t kof_ = (size_t)(kk0) + sseg;                                     \
        gl2lds16(Qbf + (size_t)(qrow0 + srow) * D + kof_, (bp_)->A + wave * 512);     \
        gl2lds16(Qbf + (size_t)(qrow0 + 64 + srow) * D + kof_,                        \
                 (bp_)->A + 2048 + wave * 512);                                       \
        gl2lds16(Xbf + (size_t)((nn0) + srow) * D + kof_, (bp_)->B + wave * 512);     \
        gl2lds16(Xbf + (size_t)((nn0) + 64 + srow) * D + kof_,                        \
                 (bp_)->B + 2048 + wave * 512);                                       \
        gl2lds16(Xbf + (size_t)((nn0) + 128 + srow) * D + kof_,                       \
                 (bp_)->B + 4096 + wave * 512);                                       \
        gl2lds16(Xbf + (size_t)((nn0) + 192 + srow) * D + kof_,                       \
                 (bp_)->B + 6144 + wave * 512);                                       \
    } while (0)

#define COMPUTE(cbp_)                                                                 \
    do {                                                                              \
        const KBuf* cb_ = (cbp_);                                                     \
        short8 af_[4], bfr_[8];                                                       \
        _Pragma("unroll") for (int ti = 0; ti < 4; ++ti)                              \
            af_[ti] = *(const short8*)&cb_->A[(wm * 64 + ti * 16 + l15) * BK + kxor]; \
        _Pragma("unroll") for (int tj = 0; tj < 8; ++tj)                              \
            bfr_[tj] = *(const short8*)&cb_->B[(wn * 128 + tj * 16 + l15) * BK + kxor];\
        _Pragma("unroll") for (int ti = 0; ti < 4; ++ti)                              \
            _Pragma("unroll") for (int tj = 0; tj < 8; ++tj)                          \
                acc[ti][tj] = __builtin_amdgcn_mfma_f32_16x16x32_bf16(                \
                    af_[ti], bfr_[tj], acc[ti][tj], 0, 0, 0);                         \
    } while (0)

// MFMA coarse scorer: 128(q) x 256(n) tile, per-wave 64x128 (4x8 frags).
// Counted-vmcnt double-buffered K pipeline (never drains in steady state),
// selection scratch aliased onto the dead K-buffer -> 48KB LDS -> 3 blocks/CU.
__global__ __launch_bounds__(256, 3) void score_mfma(
    const unsigned short* __restrict__ Qbf,
    const unsigned short* __restrict__ Xbf,
    const float* __restrict__ xsq,
    float* __restrict__ candS, int* __restrict__ candI,
    int ntiles)
{
    __shared__ KBuf st[2];                                            // 49152 B total

    const int tid = threadIdx.x;
    const int wave = tid >> 6;
    const int lane = tid & 63;
    const int quad = lane >> 4;
    const int l15 = lane & 15;
    const int wm = wave & 1;   // m-half (64 rows)
    const int wn = wave >> 1;  // n-half (128 cols)

    // XCD-aware decode: all 16 q-blocks of a chunk share bid&7 -> same XCD,
    // so the chunk's X panels (1.56 MB) stay resident in that XCD's 4MB L2.
    const int bid = blockIdx.x;
    const int t = bid >> 3;
    const int chunk = (bid & 7) + 8 * (t >> 4);   // 0..63
    const int qt = t & 15;                        // 0..15
    const int qrow0 = qt * BM;

    // staging: lane -> LDS row (tid>>2), seg (tid&3); source k-seg XOR-swizzled.
    const int srow = tid >> 2;
    const int sseg = (((tid & 3) ^ ((tid >> 3) & 3)) * 8);
    const int kxor = ((quad ^ ((l15 >> 1) & 3)) * 8);
    const int xsw = (l15 & 7) << 2;   // scw bank swizzle (rowXOR on bits 2-4)

    float ts[MPC]; int ti8[MPC];
#pragma unroll
    for (int r = 0; r < MPC; ++r) { ts[r] = FLT_MAX; ti8[r] = -1; }

    int cur = 0;
    // prologue: stage first tile k=0 into st[0]  (6 loads in flight)
    STAGE(&st[0], chunk * BN, 0);

    for (int tile = chunk; tile < ntiles; tile += NCH) {
        const int n0 = tile * BN;
        const bool last = (tile + NCH) >= ntiles;

        f32x4 acc[4][8];
#pragma unroll
        for (int ti = 0; ti < 4; ++ti)
#pragma unroll
            for (int tj = 0; tj < 8; ++tj) acc[ti][tj] = (f32x4){0.f, 0.f, 0.f, 0.f};

        // K pipeline: barrier (prev readers done with the buffer we stage into),
        // issue next stage, counted vmcnt (waits only the PREVIOUS stage; the
        // just-issued 6 stay in flight), barrier (cur data landed), compute cur.
#pragma unroll 1
        for (int ks = 0; ks < 15; ++ks) {
            __builtin_amdgcn_s_barrier();
            STAGE(&st[cur ^ 1], n0, (ks + 1) * BK);
            asm volatile("s_waitcnt vmcnt(6)" ::: "memory");
            __builtin_amdgcn_s_barrier();
            COMPUTE(&st[cur]);
            cur ^= 1;
        }
        // k=15: prefetch NEXT TILE's k=0 (lands under selection), compute k15.
        __builtin_amdgcn_s_barrier();
        if (!last) {
            STAGE(&st[cur ^ 1], n0 + NCH * BN, 0);
            asm volatile("s_waitcnt vmcnt(6)" ::: "memory");
        } else {
            asm volatile("s_waitcnt vmcnt(0)" ::: "memory");
        }
        __builtin_amdgcn_s_barrier();
        COMPUTE(&st[cur]);
        cur ^= 1;

        // All waves done with k15 frag reads before we overwrite that buffer
        // with selection scratch. (Full sync; the per-tile vmcnt drain here is
        // one L2 latency, amortized over 16 K-steps.)
        __syncthreads();

        // Selection scratch aliases the DEAD K-buffer st[cur^1] (k15, consumed).
        // The in-flight next-tile prefetch targets st[cur] -> disjoint.
        // Each wave dumps+scans its OWN 16n x 64m region (4KB), barrier-free.
        float* scw = (float*)&st[cur ^ 1] + wave * 1024;
#pragma unroll
        for (int tj = 0; tj < 8; ++tj) {
            const float xvt = xsq[n0 + wn * 128 + tj * 16 + l15];
#pragma unroll
            for (int ti = 0; ti < 4; ++ti) {
                f32x4 a = acc[ti][tj];
                a.x += xvt; a.y += xvt; a.z += xvt; a.w += xvt;
                *(f32x4*)&scw[l15 * 64 + ((ti * 16 + quad * 4) ^ xsw)] = a;
            }
            const int cb0 = n0 + wn * 128 + tj * 16;
#pragma unroll 4
            for (int n = 0; n < 16; ++n) {
                float v = scw[n * 64 + (lane ^ ((n & 7) << 2))];
                insertK<MPC>(ts, ti8, v, cb0 + n);
            }
        }
    }

    // merge the two col-half lists per query (waves wn=0 <- wn=1), write top-8.
    // Merge scratch aliases st (16KB <= 24KB), barrier-separated from selection.
    __syncthreads();
    float (*ms)[MPC] = (float (*)[MPC])st;                    // [256][MPC] = 8KB
    int (*mi)[MPC] = (int (*)[MPC])((char*)st + 8192);        // 8KB
#pragma unroll
    for (int r = 0; r < MPC; ++r) { ms[tid][r] = ts[r]; mi[tid][r] = ti8[r]; }
    __syncthreads();
    if (wn == 0) {
#pragma unroll
        for (int r = 0; r < MPC; ++r)
            insertK<MPC>(ts, ti8, ms[tid + 128][r], mi[tid + 128][r]);
        size_t base = ((size_t)(qrow0 + wm * 64 + lane) * NCH + chunk) * MPC;
#pragma unroll
        for (int r = 0; r < MPC; ++r) { candS[base + r] = ts[r]; candI[base + r] = ti8[r]; }
    }
}

// Per query: wave-parallel merge of 64 sorted chunk-lists -> approx top-16 ->
// exact fp32 rescore -> exact top-5 -> gather + mean.
__global__ void rescore_kernel(const float* __restrict__ Q, const float* __restrict__ X,
                               const float* __restrict__ xsq,
                               const float* __restrict__ candS, const int* __restrict__ candI,
                               float* __restrict__ out) {
    const int b = blockIdx.x;
    const int tid = threadIdx.x;
    const int wave = tid >> 6;
    const int lane = tid & 63;
    __shared__ int exI[TR];
    __shared__ float exS[TR];
    __shared__ int top5[5];

    if (wave == 0) {
        const float* cs = candS + (size_t)b * NCH * MPC;
        const int* ci = candI + (size_t)b * NCH * MPC;
        int h = 0;
        float cur = cs[lane * MPC];
        for (int r = 0; r < TR; ++r) {
            float v = cur; int wl = lane;
#pragma unroll
            for (int off = 1; off < 64; off <<= 1) {
                float ov = __shfl_xor(v, off, 64);
                int owl = __shfl_xor(wl, off, 64);
                if (ov < v || (ov == v && owl < wl)) { v = ov; wl = owl; }
            }
            if (lane == wl) {
                exI[r] = ci[lane * MPC + h];
                ++h;
                cur = (h < MPC) ? cs[lane * MPC + h] : FLT_MAX;
            }
        }
    }
    __syncthreads();

    const float* qr = Q + (size_t)b * D;
#pragma unroll
    for (int cc = 0; cc < 4; ++cc) {
        int c = wave * 4 + cc;
        int idx = exI[c];
        const float* xr = X + (size_t)idx * D;
        float4 qa = *(const float4*)(qr + lane * 8);
        float4 qb = *(const float4*)(qr + lane * 8 + 4);
        float4 xa = *(const float4*)(xr + lane * 8);
        float4 xb = *(const float4*)(xr + lane * 8 + 4);
        float p = qa.x * xa.x + qa.y * xa.y + qa.z * xa.z + qa.w * xa.w
                + qb.x * xb.x + qb.y * xb.y + qb.z * xb.z + qb.w * xb.w;
#pragma unroll
        for (int off = 32; off > 0; off >>= 1) p += __shfl_down(p, off, 64);
        if (lane == 0) exS[c] = xsq[idx] - 2.0f * p;
    }
    __syncthreads();

    if (tid == 0) {
        float fs[5]; int fi[5];
#pragma unroll
        for (int r = 0; r < 5; ++r) { fs[r] = FLT_MAX; fi[r] = -1; }
        for (int i = 0; i < TR; ++i) insertK<5>(fs, fi, exS[i], exI[i]);
#pragma unroll
        for (int r = 0; r < 5; ++r) top5[r] = fi[r];
    }
    __syncthreads();

#pragma unroll
    for (int dd = 0; dd < 2; ++dd) {
        int d = tid + dd * 256;
        float sacc = 0.0f;
#pragma unroll
        for (int r = 0; r < 5; ++r) sacc += X[(size_t)top5[r] * D + d];
        out[(size_t)b * D + d] = sacc / 5.0f;
    }
}

extern "C" void kernel_launch(void* const* d_in, const int* in_sizes, int n_in,
                              void* d_out, int out_size, void* d_ws, size_t ws_size,
                              hipStream_t stream) {
    const float* x_enc = (const float*)d_in[0];
    const float* X_fit = (const float*)d_in[1];
    float* out = (float*)d_out;
    const int B = in_sizes[0] / D;               // 2048
    const int N = in_sizes[1] / D;               // 100000
    const int padN = ((N + BN - 1) / BN) * BN;   // 100096
    const int ntiles = padN / BN;                // 391
    const int qtiles = B / BM;                   // 16

    char* w = (char*)d_ws;
    unsigned short* Xbf = (unsigned short*)w;            w += (size_t)padN * D * 2;
    unsigned short* Qbf = (unsigned short*)w;            w += (size_t)B * D * 2;
    float* xsq = (float*)w;                              w += (size_t)padN * 4;
    float* candS = (float*)w;                            w += (size_t)B * NCH * MPC * 4;
    int* candI = (int*)w;

    hipLaunchKernelGGL(convert_x, dim3(padN / 4), dim3(256), 0, stream, X_fit, Xbf, xsq, N, padN);
    hipLaunchKernelGGL(convert_q, dim3(B / 4), dim3(256), 0, stream, x_enc, Qbf);
    hipLaunchKernelGGL(score_mfma, dim3(qtiles * NCH), dim3(256), 0, stream,
                       Qbf, Xbf, xsq, candS, candI, ntiles);
    hipLaunchKernelGGL(rescore_kernel, dim3(B), dim3(256), 0, stream,
                       x_enc, X_fit, xsq, candS, candI, out);
}

// Round 5
// 771.420 us; speedup vs baseline: 2.2011x; 2.2011x over previous
//
#include <hip/hip_runtime.h>
#include <float.h>

#define D 512
#define BM 128
#define BN 256
#define BK 32
#define NCH 64          // chunks over the point dim
#define MPC 8           // approx candidates kept per (query, chunk)
#define TR 16           // candidates exactly rescored per query

typedef __attribute__((ext_vector_type(8))) short short8;
typedef __attribute__((ext_vector_type(4))) float f32x4;
typedef const __attribute__((address_space(1))) void gv_t;
typedef __attribute__((address_space(3))) void lv_t;

__device__ __forceinline__ void gl2lds16(const void* g, void* l) {
    __builtin_amdgcn_global_load_lds((gv_t*)g, (lv_t*)l, 16, 0, 0);
}

__device__ __forceinline__ unsigned short f2bf(float f) {
    unsigned u = __float_as_uint(f);
    return (unsigned short)((u + 0x7FFF + ((u >> 16) & 1)) >> 16);
}

template <int K>
__device__ __forceinline__ void insertK(float* bs, int* bi, float v, int id) {
    if (v < bs[K - 1]) {
        bs[K - 1] = v; bi[K - 1] = id;
#pragma unroll
        for (int r = K - 1; r >= 1; --r) {
            if (bs[r] < bs[r - 1]) {
                float tf = bs[r]; bs[r] = bs[r - 1]; bs[r - 1] = tf;
                int ti = bi[r]; bi[r] = bi[r - 1]; bi[r - 1] = ti;
            }
        }
    }
}

// X fp32 -> bf16 (zero-padded rows) + exact fp32 ||x||^2 (1e30 for pad rows).
__global__ void convert_x(const float* __restrict__ X, unsigned short* __restrict__ Xbf,
                          float* __restrict__ xsq, int N, int padN) {
    int row = blockIdx.x * 4 + (threadIdx.x >> 6);
    int lane = threadIdx.x & 63;
    if (row >= padN) return;
    unsigned short ob[8];
    float s = 0.0f;
    if (row < N) {
        const float* p = X + (size_t)row * D + lane * 8;
        float4 a = *(const float4*)p;
        float4 b = *(const float4*)(p + 4);
        s = a.x * a.x + a.y * a.y + a.z * a.z + a.w * a.w
          + b.x * b.x + b.y * b.y + b.z * b.z + b.w * b.w;
        ob[0] = f2bf(a.x); ob[1] = f2bf(a.y); ob[2] = f2bf(a.z); ob[3] = f2bf(a.w);
        ob[4] = f2bf(b.x); ob[5] = f2bf(b.y); ob[6] = f2bf(b.z); ob[7] = f2bf(b.w);
    } else {
#pragma unroll
        for (int i = 0; i < 8; ++i) ob[i] = 0;
    }
    *(uint4*)(Xbf + (size_t)row * D + lane * 8) = *(uint4*)ob;
#pragma unroll
    for (int off = 32; off > 0; off >>= 1) s += __shfl_down(s, off, 64);
    if (lane == 0) xsq[row] = (row < N) ? s : 1e30f;
}

// Q fp32 -> bf16(-2*q).
__global__ void convert_q(const float* __restrict__ Q, unsigned short* __restrict__ Qbf) {
    int row = blockIdx.x * 4 + (threadIdx.x >> 6);
    int lane = threadIdx.x & 63;
    const float* p = Q + (size_t)row * D + lane * 8;
    float4 a = *(const float4*)p;
    float4 b = *(const float4*)(p + 4);
    unsigned short ob[8];
    ob[0] = f2bf(-2.0f * a.x); ob[1] = f2bf(-2.0f * a.y);
    ob[2] = f2bf(-2.0f * a.z); ob[3] = f2bf(-2.0f * a.w);
    ob[4] = f2bf(-2.0f * b.x); ob[5] = f2bf(-2.0f * b.y);
    ob[6] = f2bf(-2.0f * b.z); ob[7] = f2bf(-2.0f * b.w);
    *(uint4*)(Qbf + (size_t)row * D + lane * 8) = *(uint4*)ob;
}

struct KBuf { unsigned short A[BM * BK]; unsigned short B[BN * BK]; };  // 24576 B

// Stage one BKx(BM+BN) bf16 panel pair into LDS buffer bp_ (6 loads/wave).
// Source k-seg XOR-preswizzled so linear-LDS frag reads are bank-spread.
#define STAGE(bp_, nn0, kk0)                                                          \
    do {                                                                              \
        const size_t kof_ = (size_t)(kk0) + sseg;                                     \
        gl2lds16(Qbf + (size_t)(qrow0 + srow) * D + kof_, (bp_)->A + wave * 512);     \
        gl2lds16(Qbf + (size_t)(qrow0 + 64 + srow) * D + kof_,                        \
                 (bp_)->A + 2048 + wave * 512);                                       \
        gl2lds16(Xbf + (size_t)((nn0) + srow) * D + kof_, (bp_)->B + wave * 512);     \
        gl2lds16(Xbf + (size_t)((nn0) + 64 + srow) * D + kof_,                        \
                 (bp_)->B + 2048 + wave * 512);                                       \
        gl2lds16(Xbf + (size_t)((nn0) + 128 + srow) * D + kof_,                       \
                 (bp_)->B + 4096 + wave * 512);                                       \
        gl2lds16(Xbf + (size_t)((nn0) + 192 + srow) * D + kof_,                       \
                 (bp_)->B + 6144 + wave * 512);                                       \
    } while (0)

#define COMPUTE(cbp_)                                                                 \
    do {                                                                              \
        const KBuf* cb_ = (cbp_);                                                     \
        short8 af_[4], bfr_[8];                                                       \
        _Pragma("unroll") for (int ti = 0; ti < 4; ++ti)                              \
            af_[ti] = *(const short8*)&cb_->A[(wm * 64 + ti * 16 + l15) * BK + kxor]; \
        _Pragma("unroll") for (int tj = 0; tj < 8; ++tj)                              \
            bfr_[tj] = *(const short8*)&cb_->B[(wn * 128 + tj * 16 + l15) * BK + kxor];\
        _Pragma("unroll") for (int ti = 0; ti < 4; ++ti)                              \
            _Pragma("unroll") for (int tj = 0; tj < 8; ++tj)                          \
                acc[ti][tj] = __builtin_amdgcn_mfma_f32_16x16x32_bf16(                \
                    af_[ti], bfr_[tj], acc[ti][tj], 0, 0, 0);                         \
    } while (0)

// MFMA coarse scorer: 128(q) x 256(n) tile, per-wave 64x128 (4x8 frags).
// Counted-vmcnt double-buffered K pipeline (never drains in steady state),
// selection scratch aliased onto the dead K-buffer -> 48KB LDS -> 3 blocks/CU
// (LDS-limited; launch_bounds stays (256,2) so the allocator keeps 128 VGPRs --
// (256,3) made LLVM chase 6 waves/EU and spill the accumulators, r4).
__global__ __launch_bounds__(256, 2) void score_mfma(
    const unsigned short* __restrict__ Qbf,
    const unsigned short* __restrict__ Xbf,
    const float* __restrict__ xsq,
    float* __restrict__ candS, int* __restrict__ candI,
    int ntiles)
{
    __shared__ KBuf st[2];                                            // 49152 B total

    const int tid = threadIdx.x;
    const int wave = tid >> 6;
    const int lane = tid & 63;
    const int quad = lane >> 4;
    const int l15 = lane & 15;
    const int wm = wave & 1;   // m-half (64 rows)
    const int wn = wave >> 1;  // n-half (128 cols)

    // XCD-aware decode: all 16 q-blocks of a chunk share bid&7 -> same XCD,
    // so the chunk's X panels (1.56 MB) stay resident in that XCD's 4MB L2.
    const int bid = blockIdx.x;
    const int t = bid >> 3;
    const int chunk = (bid & 7) + 8 * (t >> 4);   // 0..63
    const int qt = t & 15;                        // 0..15
    const int qrow0 = qt * BM;

    // staging: lane -> LDS row (tid>>2), seg (tid&3); source k-seg XOR-swizzled.
    const int srow = tid >> 2;
    const int sseg = (((tid & 3) ^ ((tid >> 3) & 3)) * 8);
    const int kxor = ((quad ^ ((l15 >> 1) & 3)) * 8);
    const int xsw = (l15 & 7) << 2;   // scw bank swizzle (rowXOR on bits 2-4)

    float ts[MPC]; int ti8[MPC];
#pragma unroll
    for (int r = 0; r < MPC; ++r) { ts[r] = FLT_MAX; ti8[r] = -1; }

    int cur = 0;
    // prologue: stage first tile k=0 into st[0]  (6 loads in flight)
    STAGE(&st[0], chunk * BN, 0);

    for (int tile = chunk; tile < ntiles; tile += NCH) {
        const int n0 = tile * BN;
        const bool last = (tile + NCH) >= ntiles;

        f32x4 acc[4][8];
#pragma unroll
        for (int ti = 0; ti < 4; ++ti)
#pragma unroll
            for (int tj = 0; tj < 8; ++tj) acc[ti][tj] = (f32x4){0.f, 0.f, 0.f, 0.f};

        // K pipeline: barrier (prev readers done with the buffer we stage into),
        // issue next stage, counted vmcnt (waits only the PREVIOUS stage; the
        // just-issued 6 stay in flight), barrier (cur data landed), compute cur.
#pragma unroll 1
        for (int ks = 0; ks < 15; ++ks) {
            __builtin_amdgcn_s_barrier();
            STAGE(&st[cur ^ 1], n0, (ks + 1) * BK);
            asm volatile("s_waitcnt vmcnt(6)" ::: "memory");
            __builtin_amdgcn_s_barrier();
            COMPUTE(&st[cur]);
            cur ^= 1;
        }
        // k=15: prefetch NEXT TILE's k=0 (lands under selection), compute k15.
        __builtin_amdgcn_s_barrier();
        if (!last) {
            STAGE(&st[cur ^ 1], n0 + NCH * BN, 0);
            asm volatile("s_waitcnt vmcnt(6)" ::: "memory");
        } else {
            asm volatile("s_waitcnt vmcnt(0)" ::: "memory");
        }
        __builtin_amdgcn_s_barrier();
        COMPUTE(&st[cur]);
        cur ^= 1;

        // All waves done with k15 frag reads before we overwrite that buffer
        // with selection scratch. (Full sync; the per-tile vmcnt drain here is
        // one L2 latency, amortized over 16 K-steps.)
        __syncthreads();

        // Selection scratch aliases the DEAD K-buffer st[cur^1] (k15, consumed).
        // The in-flight next-tile prefetch targets st[cur] -> disjoint.
        // Each wave dumps+scans its OWN 16n x 64m region (4KB), barrier-free.
        float* scw = (float*)&st[cur ^ 1] + wave * 1024;
#pragma unroll
        for (int tj = 0; tj < 8; ++tj) {
            const float xvt = xsq[n0 + wn * 128 + tj * 16 + l15];
#pragma unroll
            for (int ti = 0; ti < 4; ++ti) {
                f32x4 a = acc[ti][tj];
                a.x += xvt; a.y += xvt; a.z += xvt; a.w += xvt;
                *(f32x4*)&scw[l15 * 64 + ((ti * 16 + quad * 4) ^ xsw)] = a;
            }
            const int cb0 = n0 + wn * 128 + tj * 16;
#pragma unroll 4
            for (int n = 0; n < 16; ++n) {
                float v = scw[n * 64 + (lane ^ ((n & 7) << 2))];
                insertK<MPC>(ts, ti8, v, cb0 + n);
            }
        }
    }

    // merge the two col-half lists per query (waves wn=0 <- wn=1), write top-8.
    // Merge scratch aliases st (16KB <= 24KB), barrier-separated from selection.
    __syncthreads();
    float (*ms)[MPC] = (float (*)[MPC])st;                    // [256][MPC] = 8KB
    int (*mi)[MPC] = (int (*)[MPC])((char*)st + 8192);        // 8KB
#pragma unroll
    for (int r = 0; r < MPC; ++r) { ms[tid][r] = ts[r]; mi[tid][r] = ti8[r]; }
    __syncthreads();
    if (wn == 0) {
#pragma unroll
        for (int r = 0; r < MPC; ++r)
            insertK<MPC>(ts, ti8, ms[tid + 128][r], mi[tid + 128][r]);
        size_t base = ((size_t)(qrow0 + wm * 64 + lane) * NCH + chunk) * MPC;
#pragma unroll
        for (int r = 0; r < MPC; ++r) { candS[base + r] = ts[r]; candI[base + r] = ti8[r]; }
    }
}

// Per query: wave-parallel merge of 64 sorted chunk-lists -> approx top-16 ->
// exact fp32 rescore -> exact top-5 -> gather + mean.
__global__ void rescore_kernel(const float* __restrict__ Q, const float* __restrict__ X,
                               const float* __restrict__ xsq,
                               const float* __restrict__ candS, const int* __restrict__ candI,
                               float* __restrict__ out) {
    const int b = blockIdx.x;
    const int tid = threadIdx.x;
    const int wave = tid >> 6;
    const int lane = tid & 63;
    __shared__ int exI[TR];
    __shared__ float exS[TR];
    __shared__ int top5[5];

    if (wave == 0) {
        const float* cs = candS + (size_t)b * NCH * MPC;
        const int* ci = candI + (size_t)b * NCH * MPC;
        int h = 0;
        float cur = cs[lane * MPC];
        for (int r = 0; r < TR; ++r) {
            float v = cur; int wl = lane;
#pragma unroll
            for (int off = 1; off < 64; off <<= 1) {
                float ov = __shfl_xor(v, off, 64);
                int owl = __shfl_xor(wl, off, 64);
                if (ov < v || (ov == v && owl < wl)) { v = ov; wl = owl; }
            }
            if (lane == wl) {
                exI[r] = ci[lane * MPC + h];
                ++h;
                cur = (h < MPC) ? cs[lane * MPC + h] : FLT_MAX;
            }
        }
    }
    __syncthreads();

    const float* qr = Q + (size_t)b * D;
#pragma unroll
    for (int cc = 0; cc < 4; ++cc) {
        int c = wave * 4 + cc;
        int idx = exI[c];
        const float* xr = X + (size_t)idx * D;
        float4 qa = *(const float4*)(qr + lane * 8);
        float4 qb = *(const float4*)(qr + lane * 8 + 4);
        float4 xa = *(const float4*)(xr + lane * 8);
        float4 xb = *(const float4*)(xr + lane * 8 + 4);
        float p = qa.x * xa.x + qa.y * xa.y + qa.z * xa.z + qa.w * xa.w
                + qb.x * xb.x + qb.y * xb.y + qb.z * xb.z + qb.w * xb.w;
#pragma unroll
        for (int off = 32; off > 0; off >>= 1) p += __shfl_down(p, off, 64);
        if (lane == 0) exS[c] = xsq[idx] - 2.0f * p;
    }
    __syncthreads();

    if (tid == 0) {
        float fs[5]; int fi[5];
#pragma unroll
        for (int r = 0; r < 5; ++r) { fs[r] = FLT_MAX; fi[r] = -1; }
        for (int i = 0; i < TR; ++i) insertK<5>(fs, fi, exS[i], exI[i]);
#pragma unroll
        for (int r = 0; r < 5; ++r) top5[r] = fi[r];
    }
    __syncthreads();

#pragma unroll
    for (int dd = 0; dd < 2; ++dd) {
        int d = tid + dd * 256;
        float sacc = 0.0f;
#pragma unroll
        for (int r = 0; r < 5; ++r) sacc += X[(size_t)top5[r] * D + d];
        out[(size_t)b * D + d] = sacc / 5.0f;
    }
}

extern "C" void kernel_launch(void* const* d_in, const int* in_sizes, int n_in,
                              void* d_out, int out_size, void* d_ws, size_t ws_size,
                              hipStream_t stream) {
    const float* x_enc = (const float*)d_in[0];
    const float* X_fit = (const float*)d_in[1];
    float* out = (float*)d_out;
    const int B = in_sizes[0] / D;               // 2048
    const int N = in_sizes[1] / D;               // 100000
    const int padN = ((N + BN - 1) / BN) * BN;   // 100096
    const int ntiles = padN / BN;                // 391
    const int qtiles = B / BM;                   // 16

    char* w = (char*)d_ws;
    unsigned short* Xbf = (unsigned short*)w;            w += (size_t)padN * D * 2;
    unsigned short* Qbf = (unsigned short*)w;            w += (size_t)B * D * 2;
    float* xsq = (float*)w;                              w += (size_t)padN * 4;
    float* candS = (float*)w;                            w += (size_t)B * NCH * MPC * 4;
    int* candI = (int*)w;

    hipLaunchKernelGGL(convert_x, dim3(padN / 4), dim3(256), 0, stream, X_fit, Xbf, xsq, N, padN);
    hipLaunchKernelGGL(convert_q, dim3(B / 4), dim3(256), 0, stream, x_enc, Qbf);
    hipLaunchKernelGGL(score_mfma, dim3(qtiles * NCH), dim3(256), 0, stream,
                       Qbf, Xbf, xsq, candS, candI, ntiles);
    hipLaunchKernelGGL(rescore_kernel, dim3(B), dim3(256), 0, stream,
                       x_enc, X_fit, xsq, candS, candI, out);
}